// Round 3
// baseline (242.181 us; speedup 1.0000x reference)
//
#include <hip/hip_runtime.h>
#include <cstdint>

#define NN   2048
#define EIN  32768
#define ETOT (EIN + NN)      // 34816
#define NB   128
#define BT   1024
#define OPB  (NN / NB)       // 16 owned output nodes / block
#define RPH  (NN / NB)       // 16 MHA rows per head per block

// workspace byte offsets
#define WS_BAR   0                    // int, own 128B line (memset each call)
#define WS_CTX   128                  // float[6144]
#define WS_VPART (128 + 6144*4)       // float[128]

__device__ __forceinline__ float aload(const float* p) {
    return __hip_atomic_load(p, __ATOMIC_RELAXED, __HIP_MEMORY_SCOPE_AGENT);
}
__device__ __forceinline__ void astore(float* p, float v) {
    __hip_atomic_store(p, v, __ATOMIC_RELAXED, __HIP_MEMORY_SCOPE_AGENT);
}

// fence-free grid barrier: all cross-block data moves via agent-scope atomics
// (write-through to coherence point), so no L2 writeback/invalidate is needed.
__device__ __forceinline__ void gbar(int* bar, int target) {
    __syncthreads();
    if (threadIdx.x == 0) {
        asm volatile("s_waitcnt vmcnt(0)" ::: "memory");   // drain our atomic stores
        __hip_atomic_fetch_add(bar, 1, __ATOMIC_RELAXED, __HIP_MEMORY_SCOPE_AGENT);
        while (__hip_atomic_load(bar, __ATOMIC_RELAXED, __HIP_MEMORY_SCOPE_AGENT) < target)
            __builtin_amdgcn_s_sleep(8);
        asm volatile("" ::: "memory");
    }
    __syncthreads();
}

__global__ __launch_bounds__(BT) void k_fused(
    const float* __restrict__ x, const int* __restrict__ ei,
    const float* __restrict__ maskp,
    const float* __restrict__ gW0, const float* __restrict__ gW,
    const float* __restrict__ atts, const float* __restrict__ attd,
    const float* __restrict__ gbias,
    const float* __restrict__ mWq, const float* __restrict__ mbq,
    const float* __restrict__ mWk, const float* __restrict__ mbk,
    const float* __restrict__ mWv, const float* __restrict__ mbv,
    const float* __restrict__ mWo, const float* __restrict__ mbo,
    const float* __restrict__ tWq, const float* __restrict__ tbq,
    const float* __restrict__ tWk, const float* __restrict__ tbk,
    const float* __restrict__ tWv, const float* __restrict__ tbv,
    const float* __restrict__ tWs, const float* __restrict__ tbs,
    const float* __restrict__ W1, const float* __restrict__ b1,
    const float* __restrict__ W2, const float* __restrict__ b2,
    const float* __restrict__ W3, const float* __restrict__ b3,
    const float* __restrict__ cW, const float* __restrict__ cb,
    char* __restrict__ ws, float* __restrict__ outp)
{
    // ---- LDS (157 KB total, 1 block/CU) ----
    __shared__ float4 hh[NN];                     // 32 KB: h (layers), later tkvA
    __shared__ unsigned short srcs[ETOT];         // 68 KB: CSR src lists
    __shared__ int offs[NN + 1];                  // 8 KB
    __shared__ __align__(16) char pool[49152];    // 48 KB overlay region
    __shared__ int   redi[16];
    __shared__ float redf[96];
    __shared__ float4 tqL[OPB], skipL[OPB];
    __shared__ float Mhd[6];                      // per-head kmax[3], kmin[3]

    int*   bar   = (int*)(ws + WS_BAR);
    float* ctx   = (float*)(ws + WS_CTX);
    float* vpart = (float*)(ws + WS_VPART);

    const int tid  = threadIdx.x;
    const int bid  = blockIdx.x;
    const int lane = tid & 63;
    const int wid  = tid >> 6;

    // ================= CSR build (block-local, redundant) =================
    {
        int* cnt = (int*)pool;
        int* cur = (int*)(pool + 8192);
        for (int i = tid; i < NN; i += BT) cnt[i] = 0;
        if (tid < NN - BT) cnt[BT + tid] = 0;   // (NN==2*BT)
        __syncthreads();
        for (int e = tid; e < ETOT; e += BT) {
            int d = (e < EIN) ? ei[EIN + e] : (e - EIN);
            atomicAdd(&cnt[d], 1);
        }
        __syncthreads();
        // exclusive scan of 2048 counts (2 per thread)
        int c0 = cnt[2*tid], c1 = cnt[2*tid + 1];
        int pairv = c0 + c1;
        int v = pairv;
        #pragma unroll
        for (int d = 1; d < 64; d <<= 1) {
            int u = __shfl_up(v, d);
            if (lane >= d) v += u;
        }
        if (lane == 63) redi[wid] = v;
        __syncthreads();
        if (wid == 0 && lane < 16) {
            int t = redi[lane];
            #pragma unroll
            for (int d = 1; d < 16; d <<= 1) {
                int u = __shfl_up(t, d);
                if (lane >= d) t += u;
            }
            redi[lane] = t;
        }
        __syncthreads();
        int base = (wid ? redi[wid - 1] : 0) + (v - pairv);
        offs[2*tid]     = base;
        offs[2*tid + 1] = base + c0;
        if (tid == BT - 1) offs[NN] = base + pairv;
        __syncthreads();
        for (int i = tid; i < NN; i += BT) cur[i] = offs[i];
        if (tid < NN - BT) cur[BT + tid] = offs[BT + tid];
        __syncthreads();
        for (int e = tid; e < ETOT; e += BT) {
            int s = (e < EIN) ? ei[e]       : (e - EIN);
            int d = (e < EIN) ? ei[EIN + e] : (e - EIN);
            int p = atomicAdd(&cur[d], 1);
            srcs[p] = (unsigned short)s;
        }
        // h0 init
        #pragma unroll
        for (int i = 0; i < 2; i++) {
            int n = tid + i * BT;
            hh[n] = make_float4(x[3*n], x[3*n+1], x[3*n+2], 0.f);
        }
        __syncthreads();
    }

    // ================= 10 GAT layers (block-local, redundant) =================
    {
        float4* hw4 = (float4*)pool;               // 32 KB
        float*  ads = (float*)(pool + 32768);      // 8 KB
        for (int l = 0; l < 10; l++) {
            const float* W = l ? (gW + (l - 1) * 9) : gW0;
            float w00=W[0],w01=W[1],w02=W[2],w10=W[3],w11=W[4],w12=W[5],w20=W[6],w21=W[7],w22=W[8];
            float s0=atts[l*3],s1=atts[l*3+1],s2=atts[l*3+2];
            float d0=attd[l*3],d1=attd[l*3+1],d2=attd[l*3+2];
            float b0=gbias[l*3],bb1=gbias[l*3+1],bb2=gbias[l*3+2];
            #pragma unroll
            for (int i = 0; i < 2; i++) {
                int n = tid + i * BT;
                float4 hv = hh[n];
                float p0 = hv.x*w00 + hv.y*w10 + hv.z*w20;
                float p1 = hv.x*w01 + hv.y*w11 + hv.z*w21;
                float p2 = hv.x*w02 + hv.y*w12 + hv.z*w22;
                hw4[n] = make_float4(p0, p1, p2, p0*s0 + p1*s1 + p2*s2);
                ads[n] = p0*d0 + p1*d1 + p2*d2;
            }
            __syncthreads();
            int g = tid >> 3, sub = tid & 7;
            for (int jj = 0; jj < 16; jj++) {
                int d = g + jj * 128;
                int ps = offs[d], pe = offs[d + 1];
                float ad = ads[d];
                float m = -1e30f, se = 0.f, a0 = 0.f, a1 = 0.f, a2 = 0.f;
                for (int p = ps + sub; p < pe; p += 8) {
                    int s = srcs[p];
                    float4 hs = hw4[s];
                    float lg = hs.w + ad;
                    lg = (lg > 0.f) ? lg : 0.2f * lg;
                    float nm = fmaxf(m, lg);
                    float rr = __expf(m - nm);
                    float wg = __expf(lg - nm);
                    se = se*rr + wg;
                    a0 = a0*rr + wg*hs.x;
                    a1 = a1*rr + wg*hs.y;
                    a2 = a2*rr + wg*hs.z;
                    m = nm;
                }
                #pragma unroll
                for (int dd = 1; dd < 8; dd <<= 1) {
                    float m2 = __shfl_xor(m, dd), se2 = __shfl_xor(se, dd);
                    float q0 = __shfl_xor(a0, dd), q1 = __shfl_xor(a1, dd), q2 = __shfl_xor(a2, dd);
                    float nm = fmaxf(m, m2);
                    float f1 = __expf(m - nm), f2 = __expf(m2 - nm);
                    se = se*f1 + se2*f2;
                    a0 = a0*f1 + q0*f2; a1 = a1*f1 + q1*f2; a2 = a2*f1 + q2*f2;
                    m = nm;
                }
                if (sub == 0) {
                    float inv = 1.f / (se + 1e-16f);
                    float o0 = a0*inv + b0;
                    float o1 = a1*inv + bb1;
                    float o2 = a2*inv + bb2;
                    if (l < 9) { o0 = fmaxf(o0,0.f); o1 = fmaxf(o1,0.f); o2 = fmaxf(o2,0.f); }
                    hh[d] = make_float4(o0, o1, o2, 0.f);
                }
            }
            __syncthreads();
        }
    }

    // ================= k/v projections + per-head kmax/kmin (redundant) =================
    {
        float* kk = (float*)pool;                 // 24 KB
        float* vv = (float*)(pool + 24576);       // 24 KB
        float kmx[3] = {-3e38f,-3e38f,-3e38f}, kmn[3] = {3e38f,3e38f,3e38f};
        #pragma unroll
        for (int i = 0; i < 2; i++) {
            int n = tid + i * BT;
            float4 g = hh[n];
            #pragma unroll
            for (int c = 0; c < 3; c++) {
                float kvv = g.x*mWk[c] + g.y*mWk[3+c] + g.z*mWk[6+c] + mbk[c];
                float vvv = g.x*mWv[c] + g.y*mWv[3+c] + g.z*mWv[6+c] + mbv[c];
                kk[c*NN + n] = kvv; vv[c*NN + n] = vvv;
                kmx[c] = fmaxf(kmx[c], kvv); kmn[c] = fminf(kmn[c], kvv);
            }
        }
        #pragma unroll
        for (int c = 0; c < 3; c++) {
            #pragma unroll
            for (int d = 1; d < 64; d <<= 1) {
                kmx[c] = fmaxf(kmx[c], __shfl_xor(kmx[c], d));
                kmn[c] = fminf(kmn[c], __shfl_xor(kmn[c], d));
            }
        }
        if (lane == 0) {
            #pragma unroll
            for (int c = 0; c < 3; c++) {
                redf[wid*6 + c]     = kmx[c];
                redf[wid*6 + 3 + c] = kmn[c];
            }
        }
        __syncthreads();
        if (tid < 6) {
            bool ismax = tid < 3;
            float acc = ismax ? -3e38f : 3e38f;
            for (int w2 = 0; w2 < 16; w2++) {
                float t = redf[w2*6 + tid];
                acc = ismax ? fmaxf(acc, t) : fminf(acc, t);
            }
            Mhd[tid] = acc;
        }
        __syncthreads();

        // ---- MHA: 12 waves, each 4 rows of one head, k/v from LDS ----
        if (wid < 12) {
            int h = wid >> 2;
            int nb = bid * RPH + (wid & 3) * 4;
            float q[4], M[4], se[4], sv[4];
            #pragma unroll
            for (int i = 0; i < 4; i++) {
                float4 g = hh[nb + i];
                q[i] = g.x*mWq[h] + g.y*mWq[3+h] + g.z*mWq[6+h] + mbq[h];
                M[i] = (q[i] >= 0.f) ? q[i]*Mhd[h] : q[i]*Mhd[3+h];
                se[i] = 0.f; sv[i] = 0.f;
            }
            const float* kp = kk + h*NN;
            const float* vp = vv + h*NN;
            for (int mc = lane; mc < NN; mc += 64) {
                float kx = kp[mc], vx = vp[mc];
                #pragma unroll
                for (int i = 0; i < 4; i++) {
                    float e = __expf(q[i]*kx - M[i]);
                    se[i] += e; sv[i] = fmaf(e, vx, sv[i]);
                }
            }
            #pragma unroll
            for (int d = 32; d; d >>= 1) {
                #pragma unroll
                for (int i = 0; i < 4; i++) {
                    se[i] += __shfl_xor(se[i], d);
                    sv[i] += __shfl_xor(sv[i], d);
                }
            }
            if (lane == 0) {
                #pragma unroll
                for (int i = 0; i < 4; i++)
                    astore(&ctx[h*NN + nb + i], sv[i] / se[i]);
            }
        }
    }
    gbar(bar, NB);          // barrier #1: ctx ready

    // ================= post: res + TC projections (redundant) =================
    {
        float2* tkvB = (float2*)pool;             // 16 KB (kk/vv dead)
        #pragma unroll
        for (int i = 0; i < 2; i++) {
            int n = tid + i * BT;
            float c0 = aload(&ctx[n]);
            float c1 = aload(&ctx[NN + n]);
            float c2 = aload(&ctx[2*NN + n]);
            float r0 = c0*mWo[0] + c1*mWo[3] + c2*mWo[6] + mbo[0];
            float r1 = c0*mWo[1] + c1*mWo[4] + c2*mWo[7] + mbo[1];
            float r2 = c0*mWo[2] + c1*mWo[5] + c2*mWo[8] + mbo[2];
            float k0 = r0*tWk[0] + r1*tWk[3] + r2*tWk[6] + tbk[0];
            float k1 = r0*tWk[1] + r1*tWk[4] + r2*tWk[7] + tbk[1];
            float k2 = r0*tWk[2] + r1*tWk[5] + r2*tWk[8] + tbk[2];
            float v0 = r0*tWv[0] + r1*tWv[3] + r2*tWv[6] + tbv[0];
            float v1 = r0*tWv[1] + r1*tWv[4] + r2*tWv[7] + tbv[1];
            float v2 = r0*tWv[2] + r1*tWv[5] + r2*tWv[8] + tbv[2];
            hh[n] = make_float4(k0, k1, k2, v0);
            tkvB[n] = make_float2(v1, v2);
            unsigned rel = (unsigned)(n - bid * OPB);
            if (rel < OPB) {
                float q0 = r0*tWq[0] + r1*tWq[3] + r2*tWq[6] + tbq[0];
                float q1 = r0*tWq[1] + r1*tWq[4] + r2*tWq[7] + tbq[1];
                float q2 = r0*tWq[2] + r1*tWq[5] + r2*tWq[8] + tbq[2];
                tqL[rel] = make_float4(q0, q1, q2, 0.f);
                float s0 = r0*tWs[0] + r1*tWs[3] + r2*tWs[6] + tbs[0];
                float s1 = r0*tWs[1] + r1*tWs[4] + r2*tWs[7] + tbs[1];
                float s2 = r0*tWs[2] + r1*tWs[5] + r2*tWs[8] + tbs[2];
                skipL[rel] = make_float4(s0, s1, s2, 0.f);
            }
        }
        __syncthreads();

        // ---- TC edge pass + MLP + mask for 16 owned nodes ----
        if (tid < OPB * 8) {
            int j = tid >> 3, sub = tid & 7;
            int d = bid * OPB + j;
            float4 qv = tqL[j];
            int ps = offs[d], pe = offs[d + 1];
            float m = -1e30f, se = 0.f, a0 = 0.f, a1 = 0.f, a2 = 0.f;
            for (int p = ps + sub; p < pe; p += 8) {
                int s = srcs[p];
                float4 A = hh[s];
                float2 B = tkvB[s];
                float lg = (qv.x*A.x + qv.y*A.y + qv.z*A.z) * 0.5773502691896258f;
                float nm = fmaxf(m, lg);
                float rr = __expf(m - nm);
                float wg = __expf(lg - nm);
                se = se*rr + wg;
                a0 = a0*rr + wg*A.w;
                a1 = a1*rr + wg*B.x;
                a2 = a2*rr + wg*B.y;
                m = nm;
            }
            #pragma unroll
            for (int dd = 1; dd < 8; dd <<= 1) {
                float m2 = __shfl_xor(m, dd), se2 = __shfl_xor(se, dd);
                float q0 = __shfl_xor(a0, dd), q1 = __shfl_xor(a1, dd), q2 = __shfl_xor(a2, dd);
                float nm = fmaxf(m, m2);
                float f1 = __expf(m - nm), f2 = __expf(m2 - nm);
                se = se*f1 + se2*f2;
                a0 = a0*f1 + q0*f2; a1 = a1*f1 + q1*f2; a2 = a2*f1 + q2*f2;
                m = nm;
            }
            float inv = 1.f / (se + 1e-16f);
            float4 sk = skipL[j];
            float o0 = a0*inv + sk.x;
            float o1 = a1*inv + sk.y;
            float o2 = a2*inv + sk.z;
            float h1v[16];
            #pragma unroll
            for (int k = 0; k < 16; k++)
                h1v[k] = fmaxf(o0*W1[k] + o1*W1[16+k] + o2*W1[32+k] + b1[k], 0.f);
            float racc = 0.f;
            #pragma unroll
            for (int jc0 = 0; jc0 < 4; jc0++) {
                int jc = sub*4 + jc0;
                float t = b2[jc];
                #pragma unroll
                for (int k = 0; k < 16; k++) t = fmaf(h1v[k], W2[k*32 + jc], t);
                racc = fmaf(fmaxf(t, 0.f), W3[jc], racc);
            }
            racc += __shfl_xor(racc, 1);
            racc += __shfl_xor(racc, 2);
            racc += __shfl_xor(racc, 4);
            if (sub == 0) {
                float resv = racc + b3[0];
                outp[d] = resv * maskp[d];
                redf[j] = resv;
            }
        }
        __syncthreads();
        if (tid == 0) {
            float s = 0.f;
            for (int j = 0; j < OPB; j++) s += redf[j];
            astore(&vpart[bid], s);
        }
    }
    gbar(bar, 2 * NB);      // barrier #2: critic partials ready

    if (bid == 0) {
        float* pv = (float*)pool;
        if (tid < NB) pv[tid] = aload(&vpart[tid]);
        __syncthreads();
        if (tid == 0) {
            float s = 0.f;
            for (int b = 0; b < NB; b++) s += pv[b];
            outp[NN] = cW[0] * (s / (float)NN) + cb[0];
        }
    }
}

// ---------------------------------------------------------------------------
extern "C" void kernel_launch(void* const* d_in, const int* in_sizes, int n_in,
                              void* d_out, int out_size, void* d_ws, size_t ws_size,
                              hipStream_t stream)
{
    const float* x    = (const float*)d_in[0];
    const int*   ei   = (const int*)  d_in[1];
    const float* mask = (const float*)d_in[2];
    const float* gW0  = (const float*)d_in[3];
    const float* gW   = (const float*)d_in[4];
    const float* atts = (const float*)d_in[5];
    const float* attd = (const float*)d_in[6];
    const float* gbias= (const float*)d_in[7];
    const float* mWq = (const float*)d_in[8];  const float* mbq = (const float*)d_in[9];
    const float* mWk = (const float*)d_in[10]; const float* mbk = (const float*)d_in[11];
    const float* mWv = (const float*)d_in[12]; const float* mbv = (const float*)d_in[13];
    const float* mWo = (const float*)d_in[14]; const float* mbo = (const float*)d_in[15];
    const float* tWq = (const float*)d_in[16]; const float* tbq = (const float*)d_in[17];
    const float* tWk = (const float*)d_in[18]; const float* tbk = (const float*)d_in[19];
    const float* tWv = (const float*)d_in[20]; const float* tbv = (const float*)d_in[21];
    const float* tWs = (const float*)d_in[22]; const float* tbs = (const float*)d_in[23];
    const float* W1  = (const float*)d_in[24]; const float* b1  = (const float*)d_in[25];
    const float* W2  = (const float*)d_in[26]; const float* b2  = (const float*)d_in[27];
    const float* W3  = (const float*)d_in[28]; const float* b3  = (const float*)d_in[29];
    const float* cW  = (const float*)d_in[30]; const float* cb  = (const float*)d_in[31];

    // reset only the barrier counter line (graph-safe)
    hipMemsetAsync(d_ws, 0, 128, stream);

    k_fused<<<NB, BT, 0, stream>>>(x, ei, mask, gW0, gW, atts, attd, gbias,
                                   mWq, mbq, mWk, mbk, mWv, mbv, mWo, mbo,
                                   tWq, tbq, tWk, tbk, tWv, tbv, tWs, tbs,
                                   W1, b1, W2, b2, W3, b3, cW, cb,
                                   (char*)d_ws, (float*)d_out);
}

// Round 4
// 89.319 us; speedup vs baseline: 2.7114x; 2.7114x over previous
//
#include <hip/hip_runtime.h>
#include <cstdint>

#define NN   2048
#define EIN  32768
#define NB   64
#define BT   1024
#define OPB  32            // owned dst nodes per block
#define ECAP 4096
#define RS3  0.5773502691896258f

// ---- workspace byte offsets ----
#define WS_BAR   0                      // int (own 128B line, memset per call)
#define WS_HA    128                    // float4[2048]
#define WS_HB    (WS_HA + 32768)        // float4[2048]
#define WS_TKA   (WS_HB + 32768)        // float4[2048] (k0,k1,k2,v0)
#define WS_TKB   (WS_TKA + 32768)       // float2[2048] (v1,v2)
#define WS_VPART (WS_TKB + 16384)       // float[64]

// ---- coherent (agent-scope, relaxed) load/store helpers ----
static __device__ __forceinline__ uint64_t cload64(const void* p) {
    return __hip_atomic_load((const uint64_t*)p, __ATOMIC_RELAXED, __HIP_MEMORY_SCOPE_AGENT);
}
static __device__ __forceinline__ void cstore64(void* p, uint64_t v) {
    __hip_atomic_store((uint64_t*)p, v, __ATOMIC_RELAXED, __HIP_MEMORY_SCOPE_AGENT);
}
static __device__ __forceinline__ float4 cloadf4(const float4* p) {
    union { float4 f; uint64_t u[2]; } c;
    c.u[0] = cload64(p); c.u[1] = cload64((const char*)p + 8);
    return c.f;
}
static __device__ __forceinline__ void cstoref4(float4* p, float4 v) {
    union { float4 f; uint64_t u[2]; } c; c.f = v;
    cstore64(p, c.u[0]); cstore64((char*)p + 8, c.u[1]);
}
static __device__ __forceinline__ float2 cloadf2(const float2* p) {
    union { float2 f; uint64_t u; } c; c.u = cload64(p); return c.f;
}
static __device__ __forceinline__ void cstoref2(float2* p, float2 v) {
    union { float2 f; uint64_t u; } c; c.f = v; cstore64(p, c.u);
}
static __device__ __forceinline__ float cloadf(const float* p) {
    union { float f; uint32_t u; } c;
    c.u = __hip_atomic_load((const uint32_t*)p, __ATOMIC_RELAXED, __HIP_MEMORY_SCOPE_AGENT);
    return c.f;
}
static __device__ __forceinline__ void cstoref(float* p, float v) {
    union { float f; uint32_t u; } c; c.f = v;
    __hip_atomic_store((uint32_t*)p, c.u, __ATOMIC_RELAXED, __HIP_MEMORY_SCOPE_AGENT);
}

// fence-free grid barrier (all cross-block data moves via agent-scope atomics;
// __syncthreads drains each wave's outstanding stores before s_barrier)
static __device__ __forceinline__ void gbar(int* bar, int target) {
    __syncthreads();
    if (threadIdx.x == 0) {
        __hip_atomic_fetch_add(bar, 1, __ATOMIC_RELAXED, __HIP_MEMORY_SCOPE_AGENT);
        while (__hip_atomic_load(bar, __ATOMIC_RELAXED, __HIP_MEMORY_SCOPE_AGENT) < target)
            __builtin_amdgcn_s_sleep(4);
    }
    __syncthreads();
}

__global__ __launch_bounds__(BT) void k_fused(
    const float* __restrict__ x, const int* __restrict__ ei,
    const float* __restrict__ maskp,
    const float* __restrict__ gW0, const float* __restrict__ gW,
    const float* __restrict__ atts, const float* __restrict__ attd,
    const float* __restrict__ gbias,
    const float* __restrict__ mWq, const float* __restrict__ mbq,
    const float* __restrict__ mWk, const float* __restrict__ mbk,
    const float* __restrict__ mWv, const float* __restrict__ mbv,
    const float* __restrict__ mWo, const float* __restrict__ mbo,
    const float* __restrict__ tWq, const float* __restrict__ tbq,
    const float* __restrict__ tWk, const float* __restrict__ tbk,
    const float* __restrict__ tWv, const float* __restrict__ tbv,
    const float* __restrict__ tWs, const float* __restrict__ tbs,
    const float* __restrict__ W1, const float* __restrict__ b1,
    const float* __restrict__ W2, const float* __restrict__ b2,
    const float* __restrict__ W3, const float* __restrict__ b3,
    const float* __restrict__ cW, const float* __restrict__ cb,
    char* __restrict__ ws, float* __restrict__ outp)
{
    __shared__ float4 hw4[NN];                    // 32 KB: projected (hW, a_src), all nodes
    __shared__ __align__(16) char pool[49152];    // 48 KB: kk/vv (MHA) or tkvA/tkvB (TC)
    __shared__ unsigned short srcs[ECAP];         // 8 KB: own CSR src lists
    __shared__ int   offs[OPB + 1];
    __shared__ int   cntL[OPB];
    __shared__ int   curL[OPB];
    __shared__ float adL[OPB];
    __shared__ float4 ownH[OPB], tqL[OPB], skipL[OPB];
    __shared__ float ctxL[3][OPB];
    __shared__ float redf[96];
    __shared__ float resL[OPB];
    __shared__ float Mhd[6];

    int*    bar   = (int*)(ws + WS_BAR);
    float4* ha    = (float4*)(ws + WS_HA);
    float4* hb    = (float4*)(ws + WS_HB);
    float4* tka   = (float4*)(ws + WS_TKA);
    float2* tkb   = (float2*)(ws + WS_TKB);
    float*  vpart = (float*)(ws + WS_VPART);

    const int tid  = threadIdx.x;
    const int bid  = blockIdx.x;
    const int lane = tid & 63;
    const int wid  = tid >> 6;
    const int R0   = bid * OPB;

    // ================= own-slice CSR build (no global sync, no global atomics) =================
    if (tid < OPB) cntL[tid] = 1;                 // self-loop included
    __syncthreads();
    for (int e = tid; e < EIN; e += BT) {
        unsigned rel = (unsigned)(ei[EIN + e] - R0);
        if (rel < OPB) atomicAdd(&cntL[rel], 1);
    }
    __syncthreads();
    if (tid < 64) {
        int c = (tid < OPB) ? cntL[tid] : 0;
        int v = c;
        #pragma unroll
        for (int d = 1; d < 32; d <<= 1) {
            int u = __shfl_up(v, d);
            if (tid >= d) v += u;
        }
        if (tid < OPB) {
            offs[tid + 1] = v;
            curL[tid] = v - c + 1;                        // self occupies slot (v-c)
            srcs[v - c] = (unsigned short)(R0 + tid);
        }
        if (tid == 0) offs[0] = 0;
    }
    __syncthreads();
    for (int e = tid; e < EIN; e += BT) {
        unsigned rel = (unsigned)(ei[EIN + e] - R0);
        if (rel < OPB) {
            int p = atomicAdd(&curL[rel], 1);
            if (p < ECAP) srcs[p] = (unsigned short)ei[e];
        }
    }
    __syncthreads();

    // ================= 10 GAT layers: replicated node pass, distributed edge pass =================
    for (int l = 0; l < 10; ++l) {
        float4* hprev = (l & 1) ? ha : hb;   // valid for l>=1
        float4* hcur  = (l & 1) ? hb : ha;
        const float* W = l ? (gW + (l - 1) * 9) : gW0;
        float w00=W[0],w01=W[1],w02=W[2],w10=W[3],w11=W[4],w12=W[5],w20=W[6],w21=W[7],w22=W[8];
        float s0=atts[3*l],s1=atts[3*l+1],s2=atts[3*l+2];
        float d0=attd[3*l],d1=attd[3*l+1],d2=attd[3*l+2];
        float bb0=gbias[3*l],bb1=gbias[3*l+1],bb2=gbias[3*l+2];
        #pragma unroll
        for (int i = 0; i < 2; ++i) {
            int n = tid + i * BT;
            float hx, hy, hz;
            if (l == 0) { hx = x[3*n]; hy = x[3*n+1]; hz = x[3*n+2]; }
            else { float4 g = cloadf4(&hprev[n]); hx = g.x; hy = g.y; hz = g.z; }
            float p0 = fmaf(hx, w00, fmaf(hy, w10, hz * w20));
            float p1 = fmaf(hx, w01, fmaf(hy, w11, hz * w21));
            float p2 = fmaf(hx, w02, fmaf(hy, w12, hz * w22));
            hw4[n] = make_float4(p0, p1, p2, fmaf(p0, s0, fmaf(p1, s1, p2 * s2)));
            unsigned rel = (unsigned)(n - R0);
            if (rel < OPB) adL[rel] = fmaf(p0, d0, fmaf(p1, d1, p2 * d2));
        }
        __syncthreads();
        {
            int j = tid >> 5, sub = tid & 31;
            int ps = offs[j], pe = offs[j + 1];
            float ad = adL[j];
            float m = -1e30f, se = 0.f, a0 = 0.f, a1 = 0.f, a2 = 0.f;
            for (int p = ps + sub; p < pe; p += 32) {
                float4 hs = hw4[srcs[p]];
                float lg = hs.w + ad;
                lg = (lg > 0.f) ? lg : 0.2f * lg;
                float nm = fmaxf(m, lg);
                float rr = __expf(m - nm);
                float wg = __expf(lg - nm);
                se = se*rr + wg;
                a0 = a0*rr + wg*hs.x;
                a1 = a1*rr + wg*hs.y;
                a2 = a2*rr + wg*hs.z;
                m = nm;
            }
            #pragma unroll
            for (int d = 1; d < 32; d <<= 1) {
                float m2 = __shfl_xor(m, d), se2 = __shfl_xor(se, d);
                float q0 = __shfl_xor(a0, d), q1 = __shfl_xor(a1, d), q2 = __shfl_xor(a2, d);
                float nm = fmaxf(m, m2);
                float f1 = __expf(m - nm), f2 = __expf(m2 - nm);
                se = se*f1 + se2*f2;
                a0 = a0*f1 + q0*f2; a1 = a1*f1 + q1*f2; a2 = a2*f1 + q2*f2;
                m = nm;
            }
            if (sub == 0) {
                float inv = 1.f / (se + 1e-16f);
                float o0 = a0*inv + bb0;
                float o1 = a1*inv + bb1;
                float o2 = a2*inv + bb2;
                if (l < 9) { o0 = fmaxf(o0,0.f); o1 = fmaxf(o1,0.f); o2 = fmaxf(o2,0.f); }
                cstoref4(&hcur[R0 + j], make_float4(o0, o1, o2, 0.f));
            }
        }
        gbar(bar, NB * (l + 1));
    }

    // ================= MHA: replicated k/v + kmax/kmin, distributed rows =================
    {
        float* kk = (float*)pool;                 // 24 KB
        float* vv = (float*)(pool + 24576);       // 24 KB
        float kmx[3] = {-3e38f,-3e38f,-3e38f}, kmn[3] = {3e38f,3e38f,3e38f};
        #pragma unroll
        for (int i = 0; i < 2; ++i) {
            int n = tid + i * BT;
            float4 g = cloadf4(&hb[n]);           // final h (layer 9 wrote hb)
            unsigned rel = (unsigned)(n - R0);
            if (rel < OPB) ownH[rel] = g;
            #pragma unroll
            for (int c = 0; c < 3; ++c) {
                float kv = fmaf(g.x, mWk[c], fmaf(g.y, mWk[3+c], fmaf(g.z, mWk[6+c], mbk[c])));
                float vvv= fmaf(g.x, mWv[c], fmaf(g.y, mWv[3+c], fmaf(g.z, mWv[6+c], mbv[c])));
                kk[c*NN + n] = kv; vv[c*NN + n] = vvv;
                kmx[c] = fmaxf(kmx[c], kv); kmn[c] = fminf(kmn[c], kv);
            }
        }
        #pragma unroll
        for (int c = 0; c < 3; ++c) {
            #pragma unroll
            for (int d = 1; d < 64; d <<= 1) {
                kmx[c] = fmaxf(kmx[c], __shfl_xor(kmx[c], d));
                kmn[c] = fminf(kmn[c], __shfl_xor(kmn[c], d));
            }
        }
        if (lane == 0) {
            #pragma unroll
            for (int c = 0; c < 3; ++c) {
                redf[wid*6 + c]     = kmx[c];
                redf[wid*6 + 3 + c] = kmn[c];
            }
        }
        __syncthreads();
        if (tid < 6) {
            bool ismax = tid < 3;
            float acc = ismax ? -3e38f : 3e38f;
            for (int w2 = 0; w2 < 16; ++w2) {
                float t = redf[w2*6 + tid];
                acc = ismax ? fmaxf(acc, t) : fminf(acc, t);
            }
            Mhd[tid] = acc;
        }
        __syncthreads();
        // 96 rows (3 heads x 32 own nodes) over 16 waves, 6 rows each
        #pragma unroll
        for (int jr = 0; jr < 6; ++jr) {
            int r = wid * 6 + jr;
            int h = r >> 5, i2 = r & 31;
            float4 g = ownH[i2];
            float q = fmaf(g.x, mWq[h], fmaf(g.y, mWq[3+h], fmaf(g.z, mWq[6+h], mbq[h])));
            float M = (q >= 0.f) ? q * Mhd[h] : q * Mhd[3 + h];
            const float* kp = kk + h * NN;
            const float* vp = vv + h * NN;
            float sse = 0.f, ssv = 0.f;
            for (int mc = lane; mc < NN; mc += 64) {
                float e = __expf(fmaf(q, kp[mc], -M));
                sse += e; ssv = fmaf(e, vp[mc], ssv);
            }
            #pragma unroll
            for (int d = 32; d; d >>= 1) {
                sse += __shfl_xor(sse, d); ssv += __shfl_xor(ssv, d);
            }
            if (lane == 0) ctxL[h][i2] = ssv / sse;
        }
        __syncthreads();
        // post: res + TC projections for own nodes
        if (tid < OPB) {
            int n = R0 + tid;
            float c0 = ctxL[0][tid], c1 = ctxL[1][tid], c2 = ctxL[2][tid];
            float r0 = fmaf(c0, mWo[0], fmaf(c1, mWo[3], fmaf(c2, mWo[6], mbo[0])));
            float r1 = fmaf(c0, mWo[1], fmaf(c1, mWo[4], fmaf(c2, mWo[7], mbo[1])));
            float r2 = fmaf(c0, mWo[2], fmaf(c1, mWo[5], fmaf(c2, mWo[8], mbo[2])));
            float q0 = fmaf(r0, tWq[0], fmaf(r1, tWq[3], fmaf(r2, tWq[6], tbq[0])));
            float q1 = fmaf(r0, tWq[1], fmaf(r1, tWq[4], fmaf(r2, tWq[7], tbq[1])));
            float q2 = fmaf(r0, tWq[2], fmaf(r1, tWq[5], fmaf(r2, tWq[8], tbq[2])));
            tqL[tid] = make_float4(q0, q1, q2, 0.f);
            float k0 = fmaf(r0, tWk[0], fmaf(r1, tWk[3], fmaf(r2, tWk[6], tbk[0])));
            float k1 = fmaf(r0, tWk[1], fmaf(r1, tWk[4], fmaf(r2, tWk[7], tbk[1])));
            float k2 = fmaf(r0, tWk[2], fmaf(r1, tWk[5], fmaf(r2, tWk[8], tbk[2])));
            float v0 = fmaf(r0, tWv[0], fmaf(r1, tWv[3], fmaf(r2, tWv[6], tbv[0])));
            float v1 = fmaf(r0, tWv[1], fmaf(r1, tWv[4], fmaf(r2, tWv[7], tbv[1])));
            float v2 = fmaf(r0, tWv[2], fmaf(r1, tWv[5], fmaf(r2, tWv[8], tbv[2])));
            cstoref4(&tka[n], make_float4(k0, k1, k2, v0));
            cstoref2(&tkb[n], make_float2(v1, v2));
            float s0 = fmaf(r0, tWs[0], fmaf(r1, tWs[3], fmaf(r2, tWs[6], tbs[0])));
            float s1 = fmaf(r0, tWs[1], fmaf(r1, tWs[4], fmaf(r2, tWs[7], tbs[1])));
            float s2 = fmaf(r0, tWs[2], fmaf(r1, tWs[5], fmaf(r2, tWs[8], tbs[2])));
            skipL[tid] = make_float4(s0, s1, s2, 0.f);
        }
    }
    gbar(bar, NB * 11);

    // ================= TC edge pass + MLP + outputs =================
    {
        float4* sA = (float4*)pool;               // 32 KB
        float2* sB = (float2*)(pool + 32768);     // 16 KB
        #pragma unroll
        for (int i = 0; i < 2; ++i) {
            int n = tid + i * BT;
            sA[n] = cloadf4(&tka[n]);
            sB[n] = cloadf2(&tkb[n]);
        }
        __syncthreads();
        int j = tid >> 5, sub = tid & 31;
        float4 qv = tqL[j];
        int ps = offs[j], pe = offs[j + 1];
        float m = -1e30f, se = 0.f, a0 = 0.f, a1 = 0.f, a2 = 0.f;
        for (int p = ps + sub; p < pe; p += 32) {
            int s = srcs[p];
            float4 A = sA[s];
            float2 B = sB[s];
            float lg = fmaf(qv.x, A.x, fmaf(qv.y, A.y, qv.z * A.z)) * RS3;
            float nm = fmaxf(m, lg);
            float rr = __expf(m - nm);
            float wg = __expf(lg - nm);
            se = se*rr + wg;
            a0 = a0*rr + wg*A.w;
            a1 = a1*rr + wg*B.x;
            a2 = a2*rr + wg*B.y;
            m = nm;
        }
        #pragma unroll
        for (int d = 1; d < 32; d <<= 1) {
            float m2 = __shfl_xor(m, d), se2 = __shfl_xor(se, d);
            float q0 = __shfl_xor(a0, d), q1 = __shfl_xor(a1, d), q2 = __shfl_xor(a2, d);
            float nm = fmaxf(m, m2);
            float f1 = __expf(m - nm), f2 = __expf(m2 - nm);
            se = se*f1 + se2*f2;
            a0 = a0*f1 + q0*f2; a1 = a1*f1 + q1*f2; a2 = a2*f1 + q2*f2;
            m = nm;
        }
        float inv = 1.f / (se + 1e-16f);
        float4 sk = skipL[j];
        float o0 = a0*inv + sk.x;
        float o1 = a1*inv + sk.y;
        float o2 = a2*inv + sk.z;
        // MLP 5->16->32->1: each of the 32 lanes owns one W2 column
        float h1v[16];
        #pragma unroll
        for (int k = 0; k < 16; ++k)
            h1v[k] = fmaxf(fmaf(o0, W1[k], fmaf(o1, W1[16+k], fmaf(o2, W1[32+k], b1[k]))), 0.f);
        float t = b2[sub];
        #pragma unroll
        for (int k = 0; k < 16; ++k) t = fmaf(h1v[k], W2[k*32 + sub], t);
        float racc = fmaxf(t, 0.f) * W3[sub];
        #pragma unroll
        for (int d = 1; d < 32; d <<= 1) racc += __shfl_xor(racc, d);
        float resv = racc + b3[0];
        if (sub == 0) {
            int n = R0 + j;
            outp[n] = resv * maskp[n];
            resL[j] = resv;
        }
        __syncthreads();
        if (tid == 0) {
            float s = 0.f;
            for (int u = 0; u < OPB; ++u) s += resL[u];
            cstoref(&vpart[bid], s);
        }
    }
    gbar(bar, NB * 12);

    if (bid == 0 && tid < 64) {
        float v = cloadf(&vpart[tid]);
        #pragma unroll
        for (int d = 32; d; d >>= 1) v += __shfl_xor(v, d);
        if (tid == 0) outp[NN] = fmaf(cW[0], v * (1.f / (float)NN), cb[0]);
    }
}

// ---------------------------------------------------------------------------
extern "C" void kernel_launch(void* const* d_in, const int* in_sizes, int n_in,
                              void* d_out, int out_size, void* d_ws, size_t ws_size,
                              hipStream_t stream)
{
    const float* x    = (const float*)d_in[0];
    const int*   ei   = (const int*)  d_in[1];
    const float* mask = (const float*)d_in[2];
    const float* gW0  = (const float*)d_in[3];
    const float* gW   = (const float*)d_in[4];
    const float* atts = (const float*)d_in[5];
    const float* attd = (const float*)d_in[6];
    const float* gbias= (const float*)d_in[7];
    const float* mWq = (const float*)d_in[8];  const float* mbq = (const float*)d_in[9];
    const float* mWk = (const float*)d_in[10]; const float* mbk = (const float*)d_in[11];
    const float* mWv = (const float*)d_in[12]; const float* mbv = (const float*)d_in[13];
    const float* mWo = (const float*)d_in[14]; const float* mbo = (const float*)d_in[15];
    const float* tWq = (const float*)d_in[16]; const float* tbq = (const float*)d_in[17];
    const float* tWk = (const float*)d_in[18]; const float* tbk = (const float*)d_in[19];
    const float* tWv = (const float*)d_in[20]; const float* tbv = (const float*)d_in[21];
    const float* tWs = (const float*)d_in[22]; const float* tbs = (const float*)d_in[23];
    const float* W1  = (const float*)d_in[24]; const float* b1  = (const float*)d_in[25];
    const float* W2  = (const float*)d_in[26]; const float* b2  = (const float*)d_in[27];
    const float* W3  = (const float*)d_in[28]; const float* b3  = (const float*)d_in[29];
    const float* cW  = (const float*)d_in[30]; const float* cb  = (const float*)d_in[31];

    hipMemsetAsync(d_ws, 0, 128, stream);   // barrier counter only

    k_fused<<<NB, BT, 0, stream>>>(x, ei, mask, gW0, gW, atts, attd, gbias,
                                   mWq, mbq, mWk, mbk, mWv, mbv, mWo, mbo,
                                   tWq, tbq, tWk, tbk, tWv, tbv, tWs, tbs,
                                   W1, b1, W2, b2, W3, b3, cW, cb,
                                   (char*)d_ws, (float*)d_out);
}

// Round 5
// 78.730 us; speedup vs baseline: 3.0761x; 1.1345x over previous
//
#include <hip/hip_runtime.h>
#include <cstdint>

#define NN   2048
#define EIN  32768
#define NB   64
#define BT   1024
#define OPB  32            // owned dst nodes per block
#define ECAP 2048          // per-block CSR capacity (expected ~580)
#define UCAP 1024          // unique-source capacity (expected ~520)
#define EPT  (EIN / BT)    // 32 edges scanned per thread
#define RS3  0.5773502691896258f

// ---- workspace byte offsets ----
#define WS_FLAGS 0                      // int[64] stride 32 ints (8 KB, memset)
#define WS_DONE  8192                   // int arrival counter (memset)
#define WS_HA    8448                   // float4[2048]
#define WS_HB    41216                  // float4[2048]
#define WS_TKA   73984                  // float4[2048] (k0,k1,k2,v0)
#define WS_TKB   106752                 // float2[2048] (v1,v2)
#define WS_VPART 123136                 // float[64]
#define WS_MEMSET_BYTES 8196

// ---- coherent (agent-scope, relaxed) helpers ----
static __device__ __forceinline__ uint64_t cload64(const void* p) {
    return __hip_atomic_load((const uint64_t*)p, __ATOMIC_RELAXED, __HIP_MEMORY_SCOPE_AGENT);
}
static __device__ __forceinline__ void cstore64(void* p, uint64_t v) {
    __hip_atomic_store((uint64_t*)p, v, __ATOMIC_RELAXED, __HIP_MEMORY_SCOPE_AGENT);
}
static __device__ __forceinline__ float4 cloadf4(const float4* p) {
    union { float4 f; uint64_t u[2]; } c;
    c.u[0] = cload64(p); c.u[1] = cload64((const char*)p + 8);
    return c.f;
}
static __device__ __forceinline__ void cstoref4(float4* p, float4 v) {
    union { float4 f; uint64_t u[2]; } c; c.f = v;
    cstore64(p, c.u[0]); cstore64((char*)p + 8, c.u[1]);
}
static __device__ __forceinline__ float2 cloadf2(const float2* p) {
    union { float2 f; uint64_t u; } c; c.u = cload64(p); return c.f;
}
static __device__ __forceinline__ void cstoref2(float2* p, float2 v) {
    union { float2 f; uint64_t u; } c; c.f = v; cstore64(p, c.u);
}
static __device__ __forceinline__ float cloadf(const float* p) {
    union { float f; uint32_t u; } c;
    c.u = __hip_atomic_load((const uint32_t*)p, __ATOMIC_RELAXED, __HIP_MEMORY_SCOPE_AGENT);
    return c.f;
}
static __device__ __forceinline__ void cstoref(float* p, float v) {
    union { float f; uint32_t u; } c; c.f = v;
    __hip_atomic_store((uint32_t*)p, c.u, __ATOMIC_RELAXED, __HIP_MEMORY_SCOPE_AGENT);
}

// flag-array grid barrier: each block stores its phase to its own 128B slot
// (parallel, no RMW serialization); wave 0 polls all 64 flags in one load.
// Data visibility: every wave's agent-scope stores are drained (vmcnt(0))
// at the __syncthreads barrier before the flag store.
static __device__ __forceinline__ void gbar(int* flags, int bid, int phase) {
    __syncthreads();
    if (threadIdx.x < 64) {
        if (threadIdx.x == 0) {
            asm volatile("s_waitcnt vmcnt(0)" ::: "memory");
            __hip_atomic_store(&flags[bid * 32], phase, __ATOMIC_RELAXED, __HIP_MEMORY_SCOPE_AGENT);
        }
        while (__hip_atomic_load(&flags[threadIdx.x * 32], __ATOMIC_RELAXED,
                                 __HIP_MEMORY_SCOPE_AGENT) < phase)
            __builtin_amdgcn_s_sleep(1);
    }
    __syncthreads();
}

__global__ __launch_bounds__(BT) void k_fused(
    const float* __restrict__ x, const int* __restrict__ ei,
    const float* __restrict__ maskp,
    const float* __restrict__ gW0, const float* __restrict__ gW,
    const float* __restrict__ atts, const float* __restrict__ attd,
    const float* __restrict__ gbias,
    const float* __restrict__ mWq, const float* __restrict__ mbq,
    const float* __restrict__ mWk, const float* __restrict__ mbk,
    const float* __restrict__ mWv, const float* __restrict__ mbv,
    const float* __restrict__ mWo, const float* __restrict__ mbo,
    const float* __restrict__ tWq, const float* __restrict__ tbq,
    const float* __restrict__ tWk, const float* __restrict__ tbk,
    const float* __restrict__ tWv, const float* __restrict__ tbv,
    const float* __restrict__ tWs, const float* __restrict__ tbs,
    const float* __restrict__ W1, const float* __restrict__ b1,
    const float* __restrict__ W2, const float* __restrict__ b2,
    const float* __restrict__ W3, const float* __restrict__ b3,
    const float* __restrict__ cW, const float* __restrict__ cb,
    char* __restrict__ ws, float* __restrict__ outp)
{
    __shared__ __align__(16) char pool[49152];    // MHA kk/vv 48KB; TC sAL/sBL 24KB
    __shared__ float4 hw4L[UCAP];                 // 16 KB projected unique sources
    __shared__ unsigned short srcs[ECAP];         // own CSR (remapped to local idx)
    __shared__ unsigned short uniq[UCAP];         // local idx -> global node id
    __shared__ unsigned short mark[NN];           // global node id -> local idx
    __shared__ int offs[OPB + 1];
    __shared__ int cntL[OPB], curL[OPB], dloc[OPB];
    __shared__ int uniqCnt;
    __shared__ float4 ownH[OPB], tqL[OPB], skipL[OPB];
    __shared__ float ctxL[3][OPB];
    __shared__ float redf[96];
    __shared__ float resL[OPB];
    __shared__ float Mhd[6];

    int*    flags = (int*)(ws + WS_FLAGS);
    int*    done  = (int*)(ws + WS_DONE);
    float4* ha    = (float4*)(ws + WS_HA);
    float4* hb    = (float4*)(ws + WS_HB);
    float4* tka   = (float4*)(ws + WS_TKA);
    float2* tkb   = (float2*)(ws + WS_TKB);
    float*  vpart = (float*)(ws + WS_VPART);

    const int tid  = threadIdx.x;
    const int bid  = blockIdx.x;
    const int lane = tid & 63;
    const int wid  = tid >> 6;
    const int R0   = bid * OPB;

    // ================= CSR build: one pass over ei, dsts cached in VGPRs =================
    int dcache[EPT];
    #pragma unroll
    for (int i = 0; i < EPT; ++i) dcache[i] = ei[EIN + tid + i * BT];

    if (tid < OPB) cntL[tid] = 1;                 // self-loop
    __syncthreads();
    #pragma unroll
    for (int i = 0; i < EPT; ++i) {
        unsigned rel = (unsigned)(dcache[i] - R0);
        if (rel < OPB) atomicAdd(&cntL[rel], 1);
    }
    __syncthreads();
    if (tid < 64) {
        int c = (tid < OPB) ? cntL[tid] : 0;
        int v = c;
        #pragma unroll
        for (int d = 1; d < 32; d <<= 1) {
            int u = __shfl_up(v, d);
            if (tid >= d) v += u;
        }
        if (tid < OPB) {
            offs[tid + 1] = v;
            curL[tid] = v - c + 1;                        // slot (v-c) = self-loop
            srcs[v - c] = (unsigned short)(R0 + tid);
        }
        if (tid == 0) { offs[0] = 0; uniqCnt = 0; }
    }
    __syncthreads();
    #pragma unroll
    for (int i = 0; i < EPT; ++i) {
        unsigned rel = (unsigned)(dcache[i] - R0);
        if (rel < OPB) {
            int p = atomicAdd(&curL[rel], 1);
            srcs[p] = (unsigned short)ei[tid + i * BT];
        }
    }
    // mark init
    mark[tid] = 0xFFFFu; mark[tid + BT] = 0xFFFFu;
    __syncthreads();

    // ================= dedup sources (benign races) + remap CSR =================
    const int totE = offs[OPB];
    for (int p = tid; p < totE; p += BT) {
        int s = srcs[p];
        if (mark[s] == 0xFFFFu) {
            int u = atomicAdd(&uniqCnt, 1);
            uniq[u] = (unsigned short)s;
            mark[s] = (unsigned short)u;
        }
    }
    __syncthreads();
    for (int p = tid; p < totE; p += BT) srcs[p] = mark[srcs[p]];
    if (tid < OPB) dloc[tid] = mark[R0 + tid];
    __syncthreads();
    const int UC = uniqCnt;                        // <= totE <= ~620 < UCAP

    // ================= 10 GAT layers =================
    for (int l = 0; l < 10; ++l) {
        float4* hprev = (l & 1) ? ha : hb;
        float4* hcur  = (l & 1) ? hb : ha;
        const float* W = l ? (gW + (l - 1) * 9) : gW0;
        float w00=W[0],w01=W[1],w02=W[2],w10=W[3],w11=W[4],w12=W[5],w20=W[6],w21=W[7],w22=W[8];
        float s0=atts[3*l],s1=atts[3*l+1],s2=atts[3*l+2];
        float d0=attd[3*l],d1=attd[3*l+1],d2=attd[3*l+2];
        float bb0=gbias[3*l],bb1=gbias[3*l+1],bb2=gbias[3*l+2];
        // node pass: project only this block's unique sources
        if (tid < UC) {
            int g = uniq[tid];
            float hx, hy, hz;
            if (l == 0) { hx = x[3*g]; hy = x[3*g+1]; hz = x[3*g+2]; }
            else { float4 t = cloadf4(&hprev[g]); hx = t.x; hy = t.y; hz = t.z; }
            float p0 = fmaf(hx, w00, fmaf(hy, w10, hz * w20));
            float p1 = fmaf(hx, w01, fmaf(hy, w11, hz * w21));
            float p2 = fmaf(hx, w02, fmaf(hy, w12, hz * w22));
            hw4L[tid] = make_float4(p0, p1, p2, fmaf(p0, s0, fmaf(p1, s1, p2 * s2)));
        }
        __syncthreads();
        {
            int j = tid >> 5, sub = tid & 31;
            int ps = offs[j], pe = offs[j + 1];
            float4 hd = hw4L[dloc[j]];            // broadcast LDS read
            float ad = fmaf(hd.x, d0, fmaf(hd.y, d1, hd.z * d2));
            float m = -1e30f, se = 0.f, a0 = 0.f, a1 = 0.f, a2 = 0.f;
            for (int p = ps + sub; p < pe; p += 32) {
                float4 hs = hw4L[srcs[p]];
                float lg = hs.w + ad;
                lg = (lg > 0.f) ? lg : 0.2f * lg;
                float nm = fmaxf(m, lg);
                float rr = __expf(m - nm);
                float wg = __expf(lg - nm);
                se = se*rr + wg;
                a0 = a0*rr + wg*hs.x;
                a1 = a1*rr + wg*hs.y;
                a2 = a2*rr + wg*hs.z;
                m = nm;
            }
            #pragma unroll
            for (int d = 1; d < 32; d <<= 1) {
                float m2 = __shfl_xor(m, d), se2 = __shfl_xor(se, d);
                float q0 = __shfl_xor(a0, d), q1 = __shfl_xor(a1, d), q2 = __shfl_xor(a2, d);
                float nm = fmaxf(m, m2);
                float f1 = __expf(m - nm), f2 = __expf(m2 - nm);
                se = se*f1 + se2*f2;
                a0 = a0*f1 + q0*f2; a1 = a1*f1 + q1*f2; a2 = a2*f1 + q2*f2;
                m = nm;
            }
            if (sub == 0) {
                float inv = 1.f / (se + 1e-16f);
                float o0 = a0*inv + bb0;
                float o1 = a1*inv + bb1;
                float o2 = a2*inv + bb2;
                if (l < 9) { o0 = fmaxf(o0,0.f); o1 = fmaxf(o1,0.f); o2 = fmaxf(o2,0.f); }
                cstoref4(&hcur[R0 + j], make_float4(o0, o1, o2, 0.f));
            }
        }
        gbar(flags, bid, l + 1);
    }

    // ================= MHA: replicated k/v + kmax/kmin, distributed rows =================
    {
        float* kk = (float*)pool;                 // 24 KB
        float* vv = (float*)(pool + 24576);       // 24 KB
        float kmx[3] = {-3e38f,-3e38f,-3e38f}, kmn[3] = {3e38f,3e38f,3e38f};
        #pragma unroll
        for (int i = 0; i < 2; ++i) {
            int n = tid + i * BT;
            float4 g = cloadf4(&hb[n]);           // final h (layer 9 wrote hb)
            unsigned rel = (unsigned)(n - R0);
            if (rel < OPB) ownH[rel] = g;
            #pragma unroll
            for (int c = 0; c < 3; ++c) {
                float kv = fmaf(g.x, mWk[c], fmaf(g.y, mWk[3+c], fmaf(g.z, mWk[6+c], mbk[c])));
                float vvv= fmaf(g.x, mWv[c], fmaf(g.y, mWv[3+c], fmaf(g.z, mWv[6+c], mbv[c])));
                kk[c*NN + n] = kv; vv[c*NN + n] = vvv;
                kmx[c] = fmaxf(kmx[c], kv); kmn[c] = fminf(kmn[c], vvv == vvv ? kv : kv);
            }
        }
        #pragma unroll
        for (int c = 0; c < 3; ++c) {
            #pragma unroll
            for (int d = 1; d < 64; d <<= 1) {
                kmx[c] = fmaxf(kmx[c], __shfl_xor(kmx[c], d));
                kmn[c] = fminf(kmn[c], __shfl_xor(kmn[c], d));
            }
        }
        if (lane == 0) {
            #pragma unroll
            for (int c = 0; c < 3; ++c) {
                redf[wid*6 + c]     = kmx[c];
                redf[wid*6 + 3 + c] = kmn[c];
            }
        }
        __syncthreads();
        if (tid < 6) {
            bool ismax = tid < 3;
            float acc = ismax ? -3e38f : 3e38f;
            for (int w2 = 0; w2 < 16; ++w2) {
                float t = redf[w2*6 + tid];
                acc = ismax ? fmaxf(acc, t) : fminf(acc, t);
            }
            Mhd[tid] = acc;
        }
        __syncthreads();
        // 96 rows (3 heads x 32 own nodes) over 16 waves, 6 rows each
        #pragma unroll
        for (int jr = 0; jr < 6; ++jr) {
            int r = wid * 6 + jr;
            int h = r >> 5, i2 = r & 31;
            float4 g = ownH[i2];
            float q = fmaf(g.x, mWq[h], fmaf(g.y, mWq[3+h], fmaf(g.z, mWq[6+h], mbq[h])));
            float M = (q >= 0.f) ? q * Mhd[h] : q * Mhd[3 + h];
            const float* kp = kk + h * NN;
            const float* vp = vv + h * NN;
            float sse = 0.f, ssv = 0.f;
            for (int mc = lane; mc < NN; mc += 64) {
                float e = __expf(fmaf(q, kp[mc], -M));
                sse += e; ssv = fmaf(e, vp[mc], ssv);
            }
            #pragma unroll
            for (int d = 32; d; d >>= 1) {
                sse += __shfl_xor(sse, d); ssv += __shfl_xor(ssv, d);
            }
            if (lane == 0) ctxL[h][i2] = ssv / sse;
        }
        __syncthreads();
        // post: res + TC projections for own nodes
        if (tid < OPB) {
            int n = R0 + tid;
            float c0 = ctxL[0][tid], c1 = ctxL[1][tid], c2 = ctxL[2][tid];
            float r0 = fmaf(c0, mWo[0], fmaf(c1, mWo[3], fmaf(c2, mWo[6], mbo[0])));
            float r1 = fmaf(c0, mWo[1], fmaf(c1, mWo[4], fmaf(c2, mWo[7], mbo[1])));
            float r2 = fmaf(c0, mWo[2], fmaf(c1, mWo[5], fmaf(c2, mWo[8], mbo[2])));
            float q0 = fmaf(r0, tWq[0], fmaf(r1, tWq[3], fmaf(r2, tWq[6], tbq[0])));
            float q1 = fmaf(r0, tWq[1], fmaf(r1, tWq[4], fmaf(r2, tWq[7], tbq[1])));
            float q2 = fmaf(r0, tWq[2], fmaf(r1, tWq[5], fmaf(r2, tWq[8], tbq[2])));
            tqL[tid] = make_float4(q0, q1, q2, 0.f);
            float k0 = fmaf(r0, tWk[0], fmaf(r1, tWk[3], fmaf(r2, tWk[6], tbk[0])));
            float k1 = fmaf(r0, tWk[1], fmaf(r1, tWk[4], fmaf(r2, tWk[7], tbk[1])));
            float k2 = fmaf(r0, tWk[2], fmaf(r1, tWk[5], fmaf(r2, tWk[8], tbk[2])));
            float v0 = fmaf(r0, tWv[0], fmaf(r1, tWv[3], fmaf(r2, tWv[6], tbv[0])));
            float v1 = fmaf(r0, tWv[1], fmaf(r1, tWv[4], fmaf(r2, tWv[7], tbv[1])));
            float v2 = fmaf(r0, tWv[2], fmaf(r1, tWv[5], fmaf(r2, tWv[8], tbv[2])));
            cstoref4(&tka[n], make_float4(k0, k1, k2, v0));
            cstoref2(&tkb[n], make_float2(v1, v2));
            float s0 = fmaf(r0, tWs[0], fmaf(r1, tWs[3], fmaf(r2, tWs[6], tbs[0])));
            float s1 = fmaf(r0, tWs[1], fmaf(r1, tWs[4], fmaf(r2, tWs[7], tbs[1])));
            float s2 = fmaf(r0, tWs[2], fmaf(r1, tWs[5], fmaf(r2, tWs[8], tbs[2])));
            skipL[tid] = make_float4(s0, s1, s2, 0.f);
        }
    }
    gbar(flags, bid, 11);

    // ================= TC edge pass + MLP + outputs =================
    {
        float4* sAL = (float4*)pool;              // 16 KB: unique (k,v0)
        float2* sBL = (float2*)(pool + 16384);    // 8 KB: unique (v1,v2)
        if (tid < UC) {
            int g = uniq[tid];
            sAL[tid] = cloadf4(&tka[g]);
            sBL[tid] = cloadf2(&tkb[g]);
        }
        __syncthreads();
        int j = tid >> 5, sub = tid & 31;
        float4 qv = tqL[j];
        int ps = offs[j], pe = offs[j + 1];
        float m = -1e30f, se = 0.f, a0 = 0.f, a1 = 0.f, a2 = 0.f;
        for (int p = ps + sub; p < pe; p += 32) {
            int s = srcs[p];
            float4 A = sAL[s];
            float2 B = sBL[s];
            float lg = fmaf(qv.x, A.x, fmaf(qv.y, A.y, qv.z * A.z)) * RS3;
            float nm = fmaxf(m, lg);
            float rr = __expf(m - nm);
            float wg = __expf(lg - nm);
            se = se*rr + wg;
            a0 = a0*rr + wg*A.w;
            a1 = a1*rr + wg*B.x;
            a2 = a2*rr + wg*B.y;
            m = nm;
        }
        #pragma unroll
        for (int d = 1; d < 32; d <<= 1) {
            float m2 = __shfl_xor(m, d), se2 = __shfl_xor(se, d);
            float q0 = __shfl_xor(a0, d), q1 = __shfl_xor(a1, d), q2 = __shfl_xor(a2, d);
            float nm = fmaxf(m, m2);
            float f1 = __expf(m - nm), f2 = __expf(m2 - nm);
            se = se*f1 + se2*f2;
            a0 = a0*f1 + q0*f2; a1 = a1*f1 + q1*f2; a2 = a2*f1 + q2*f2;
            m = nm;
        }
        float inv = 1.f / (se + 1e-16f);
        float4 sk = skipL[j];
        float o0 = a0*inv + sk.x;
        float o1 = a1*inv + sk.y;
        float o2 = a2*inv + sk.z;
        float h1v[16];
        #pragma unroll
        for (int k = 0; k < 16; ++k)
            h1v[k] = fmaxf(fmaf(o0, W1[k], fmaf(o1, W1[16+k], fmaf(o2, W1[32+k], b1[k]))), 0.f);
        float t = b2[sub];
        #pragma unroll
        for (int k = 0; k < 16; ++k) t = fmaf(h1v[k], W2[k*32 + sub], t);
        float racc = fmaxf(t, 0.f) * W3[sub];
        #pragma unroll
        for (int d = 1; d < 32; d <<= 1) racc += __shfl_xor(racc, d);
        float resv = racc + b3[0];
        if (sub == 0) {
            int n = R0 + j;
            outp[n] = resv * maskp[n];
            resL[j] = resv;
        }
        __syncthreads();
        // critic: last-arriving block sums all partials in fixed order
        if (tid == 0) {
            float s = 0.f;
            for (int u = 0; u < OPB; ++u) s += resL[u];
            cstoref(&vpart[bid], s);
            asm volatile("s_waitcnt vmcnt(0)" ::: "memory");
            int ticket = __hip_atomic_fetch_add(done, 1, __ATOMIC_RELAXED, __HIP_MEMORY_SCOPE_AGENT);
            if (ticket == NB - 1) {
                float tsum = 0.f;
                for (int b = 0; b < NB; ++b) tsum += cloadf(&vpart[b]);
                outp[NN] = fmaf(cW[0], tsum * (1.f / (float)NN), cb[0]);
            }
        }
    }
}

// ---------------------------------------------------------------------------
extern "C" void kernel_launch(void* const* d_in, const int* in_sizes, int n_in,
                              void* d_out, int out_size, void* d_ws, size_t ws_size,
                              hipStream_t stream)
{
    const float* x    = (const float*)d_in[0];
    const int*   ei   = (const int*)  d_in[1];
    const float* mask = (const float*)d_in[2];
    const float* gW0  = (const float*)d_in[3];
    const float* gW   = (const float*)d_in[4];
    const float* atts = (const float*)d_in[5];
    const float* attd = (const float*)d_in[6];
    const float* gbias= (const float*)d_in[7];
    const float* mWq = (const float*)d_in[8];  const float* mbq = (const float*)d_in[9];
    const float* mWk = (const float*)d_in[10]; const float* mbk = (const float*)d_in[11];
    const float* mWv = (const float*)d_in[12]; const float* mbv = (const float*)d_in[13];
    const float* mWo = (const float*)d_in[14]; const float* mbo = (const float*)d_in[15];
    const float* tWq = (const float*)d_in[16]; const float* tbq = (const float*)d_in[17];
    const float* tWk = (const float*)d_in[18]; const float* tbk = (const float*)d_in[19];
    const float* tWv = (const float*)d_in[20]; const float* tbv = (const float*)d_in[21];
    const float* tWs = (const float*)d_in[22]; const float* tbs = (const float*)d_in[23];
    const float* W1  = (const float*)d_in[24]; const float* b1  = (const float*)d_in[25];
    const float* W2  = (const float*)d_in[26]; const float* b2  = (const float*)d_in[27];
    const float* W3  = (const float*)d_in[28]; const float* b3  = (const float*)d_in[29];
    const float* cW  = (const float*)d_in[30]; const float* cb  = (const float*)d_in[31];

    hipMemsetAsync(d_ws, 0, WS_MEMSET_BYTES, stream);   // flags + arrival counter

    k_fused<<<NB, BT, 0, stream>>>(x, ei, mask, gW0, gW, atts, attd, gbias,
                                   mWq, mbq, mWk, mbk, mWv, mbv, mWo, mbo,
                                   tWq, tbq, tWk, tbk, tWv, tbv, tWs, tbs,
                                   W1, b1, W2, b2, W3, b3, cW, cb,
                                   (char*)d_ws, (float*)d_out);
}